// Round 10
// baseline (248.813 us; speedup 1.0000x reference)
//
#include <hip/hip_runtime.h>
#include <hip/hip_bf16.h>
#include <math.h>

#define TT 1024
#define HH 2048
#define EE 32
#define II 1024
#define BK2 128   // K-step (512 B per weight row per step)
#define SA2 136   // LDS row stride in bf16 elems (128 + 8 pad -> 2-way bank alias only)
#define TS2 (128 * SA2)
#define KSP 32    // router split-K chunks (K-chunk = 64)
#define MB 64     // router tokens per block

typedef __attribute__((ext_vector_type(8))) short bf16x8;
typedef __attribute__((ext_vector_type(8))) unsigned short ushort8;
typedef __attribute__((ext_vector_type(4))) float f32x4;

__device__ __forceinline__ unsigned short f2b(float f) {
    union { float f; unsigned u; } c; c.f = f;
    unsigned r = c.u + 0x7FFFu + ((c.u >> 16) & 1u);   // RNE to bf16
    return (unsigned short)(r >> 16);
}
__device__ __forceinline__ float b2f(unsigned short u) {
    union { unsigned u; float f; } c; c.u = ((unsigned)u) << 16;
    return c.f;
}
__device__ __forceinline__ unsigned cvtpk(float lo, float hi) {
    unsigned r;
    asm("v_cvt_pk_bf16_f32 %0, %1, %2" : "=v"(r) : "v"(lo), "v"(hi));
    return r;
}
__device__ __forceinline__ ushort8 pack8(float4 a, float4 b) {
    union { unsigned u[4]; ushort8 s; } cv;
    cv.u[0] = cvtpk(a.x, a.y); cv.u[1] = cvtpk(a.z, a.w);
    cv.u[2] = cvtpk(b.x, b.y); cv.u[3] = cvtpk(b.z, b.w);
    return cv.s;
}

// ---------------- x -> bf16 pre-convert ----------------
__global__ __launch_bounds__(256) void k_cvtx(const float* __restrict__ x,
                                              unsigned short* __restrict__ xb) {
    int i = blockIdx.x * 256 + threadIdx.x;        // over T*H/8
    const float4* s = (const float4*)(x + (size_t)i * 8);
    float4 v0 = s[0], v1 = s[1];
    *(ushort8*)(xb + (size_t)i * 8) = pack8(v0, v1);
}

// ---------------- router mix: split-K tiled fp32 GEMM ----------------
__global__ __launch_bounds__(256) void k_mix(const float* __restrict__ x,
                                             const float* __restrict__ wqkv,
                                             float* __restrict__ mixp) {
    __shared__ float xs[MB][68];
    __shared__ float ws_[96][68];
    const int tm0 = blockIdx.x * MB;
    const int k0 = blockIdx.y * 64;
    const int tid = threadIdx.x;
#pragma unroll
    for (int q = 0; q < 4; ++q) {
        int p = tid + q * 256;
        int row = p >> 4, c4 = (p & 15) * 4;
        *(float4*)&xs[row][c4] = *(const float4*)(x + (size_t)(tm0 + row) * HH + k0 + c4);
    }
#pragma unroll
    for (int q = 0; q < 6; ++q) {
        int p = tid + q * 256;
        int row = p >> 4, c4 = (p & 15) * 4;
        *(float4*)&ws_[row][c4] = *(const float4*)(wqkv + (size_t)row * HH + k0 + c4);
    }
    __syncthreads();
    const int tg = tid >> 4, cg = tid & 15;
    float acc[4][6];
#pragma unroll
    for (int i = 0; i < 4; ++i)
#pragma unroll
        for (int c = 0; c < 6; ++c) acc[i][c] = 0.f;
    for (int k = 0; k < 64; k += 4) {
        float4 xv[4], wv[6];
#pragma unroll
        for (int i = 0; i < 4; ++i) xv[i] = *(const float4*)&xs[tg * 4 + i][k];
#pragma unroll
        for (int c = 0; c < 6; ++c) wv[c] = *(const float4*)&ws_[cg * 6 + c][k];
#pragma unroll
        for (int i = 0; i < 4; ++i)
#pragma unroll
            for (int c = 0; c < 6; ++c)
                acc[i][c] += xv[i].x * wv[c].x + xv[i].y * wv[c].y +
                             xv[i].z * wv[c].z + xv[i].w * wv[c].w;
    }
    float* dst = mixp + ((size_t)blockIdx.y * TT + tm0) * 96;
#pragma unroll
    for (int i = 0; i < 4; ++i)
#pragma unroll
        for (int c = 0; c < 6; ++c)
            dst[(tg * 4 + i) * 96 + cg * 6 + c] = acc[i][c];
}

// ---------------- router: reduce partials + attention + top-2 + scatter ----------------
__global__ void k_router_attn(const float* __restrict__ mixp,
                              int* __restrict__ cnt,
                              int* __restrict__ tok_list,
                              float* __restrict__ wgt_list) {
    const int t = blockIdx.x;
    __shared__ float mrow[96];
    __shared__ float lg[EE];
    const int tid = threadIdx.x;
    if (tid < 96) {
        float s = 0.f;
        for (int sp = 0; sp < KSP; ++sp)          // fixed order -> deterministic
            s += mixp[((size_t)sp * TT + t) * 96 + tid];
        mrow[tid] = s;
    }
    __syncthreads();
    if (tid < EE) {
        float q = mrow[tid];
        float m = -1e30f;
        for (int f = 0; f < EE; ++f) m = fmaxf(m, q * mrow[32 + f]);
        float s = 0.f, a = 0.f;
        for (int f = 0; f < EE; ++f) {
            float ex = expf(q * mrow[32 + f] - m);
            s += ex;
            a += ex * mrow[64 + f];
        }
        lg[tid] = a / s;
    }
    __syncthreads();
    if (tid == 0) {
        int b0 = 0; float v0 = lg[0];
        for (int e2 = 1; e2 < EE; ++e2)
            if (lg[e2] > v0) { v0 = lg[e2]; b0 = e2; }
        int b1 = -1; float v1 = -1e30f;
        for (int e2 = 0; e2 < EE; ++e2)
            if (e2 != b0 && lg[e2] > v1) { v1 = lg[e2]; b1 = e2; }
        float ex = expf(v1 - v0);
        float w0 = 1.f / (1.f + ex);
        float w1 = ex / (1.f + ex);
        int p0 = atomicAdd(&cnt[b0], 1);
        tok_list[b0 * TT + p0] = t * 2 + 0;
        wgt_list[b0 * TT + p0] = w0;
        int p1 = atomicAdd(&cnt[b1], 1);
        tok_list[b1 * TT + p1] = t * 2 + 1;
        wgt_list[b1 * TT + p1] = w1;
    }
}

// XCD-locality swizzle: dispatch round-robins XCD = lin % 8 (perf heuristic only).
// Map lin -> (e, n) s.t. all 16 n-blocks of an expert share one XCD:
//   lin = e%8 + 8*(n + 16*(e/8))
__device__ __forceinline__ void swz_en(int lin, int& e, int& n) {
    int r = lin & 7, q = lin >> 3;
    e = r + 8 * (q >> 4);
    n = q & 15;
}

// ---------------- gemm1: act[entry, i0:i0+64] = silu(gate)*up*w  (fused gate/up, BK=128) ----------------
// grid (16, E): block covers 64 gate rows + 64 up rows of w1[e]; m-chunks looped in-kernel
__global__ __launch_bounds__(256, 2) void k_gemm1(
    const unsigned short* __restrict__ xb, const float* __restrict__ w1,
    const int* __restrict__ cnt, const int* __restrict__ tok_list,
    const float* __restrict__ wgt_list, unsigned short* __restrict__ act) {
    int e, nblk;
    swz_en(blockIdx.y * 16 + blockIdx.x, e, nblk);
    const int M = cnt[e];
    const int i0 = nblk * 64;

    __shared__ __align__(16) unsigned short As[TS2];
    __shared__ __align__(16) unsigned short Bs[TS2];
    __shared__ int ts[128];
    __shared__ float tw[128];

    const int tid = threadIdx.x;
    const float* w1e = w1 + (size_t)e * (2 * II) * HH;
    const int wid = tid >> 6;
    const int lane = tid & 63;
    const int wm = wid >> 1, wn = wid & 1;
    const int fr = lane & 15;
    const int kg = lane >> 4;
    const int srow = tid >> 4;          // 16 threads per row
    const int sc8 = (tid & 15) * 8;     // col offset (8 elems): 512 B/row contiguous

    ushort8 pa8[8];
    float4 pb[16];
    const ushort8 u8z = {0, 0, 0, 0, 0, 0, 0, 0};

    for (int m0 = 0; m0 < M; m0 += 128) {
        __syncthreads();                 // guard ts/tw & LDS reuse across m-chunks
        if (tid < 128) {
            int mr = m0 + tid;
            if (mr < M) {
                ts[tid] = tok_list[e * TT + mr];
                tw[tid] = wgt_list[e * TT + mr];
            } else { ts[tid] = -1; tw[tid] = 0.f; }
        }
        __syncthreads();

        f32x4 acc[4][4];
#pragma unroll
        for (int i = 0; i < 4; ++i)
#pragma unroll
            for (int j = 0; j < 4; ++j) acc[i][j] = (f32x4){0.f, 0.f, 0.f, 0.f};

#define G1_LOAD(kk)                                                              \
    do {                                                                         \
        const int kkv_ = (kk);                                                   \
        _Pragma("unroll")                                                        \
        for (int q = 0; q < 8; ++q) {                                            \
            int row = q * 16 + srow;                                             \
            int entry = ts[row];                                                 \
            pa8[q] = (entry >= 0)                                                \
                ? *(const ushort8*)(xb + (size_t)(entry >> 1) * HH + kkv_ + sc8) \
                : u8z;                                                           \
            int brow = (row < 64) ? (i0 + row) : (II + i0 + row - 64);           \
            const float* gpb_ = w1e + (size_t)brow * HH + kkv_ + sc8;            \
            pb[2 * q] = ((const float4*)gpb_)[0];                                \
            pb[2 * q + 1] = ((const float4*)gpb_)[1];                            \
        }                                                                        \
    } while (0)

#define G1_CVT()                                                                 \
    do {                                                                         \
        _Pragma("unroll")                                                        \
        for (int q = 0; q < 8; ++q) {                                            \
            int row = q * 16 + srow;                                             \
            *(ushort8*)&As[row * SA2 + sc8] = pa8[q];                            \
            *(ushort8*)&Bs[row * SA2 + sc8] = pack8(pb[2 * q], pb[2 * q + 1]);   \
        }                                                                        \
    } while (0)

        const int NS = HH / BK2;   // 16
        G1_LOAD(0);
        for (int s = 0; s < NS; ++s) {
            __syncthreads();
            G1_CVT();
            __syncthreads();
            if (s + 1 < NS) G1_LOAD((s + 1) * BK2);
#pragma unroll
            for (int kh = 0; kh < 4; ++kh) {
                const int kb = kh * 32 + kg * 8;
                bf16x8 a[4], b[4];
#pragma unroll
                for (int i = 0; i < 4; ++i)
                    a[i] = *(const bf16x8*)&As[(wm * 64 + i * 16 + fr) * SA2 + kb];
#pragma unroll
                for (int j = 0; j < 4; ++j)
                    b[j] = *(const bf16x8*)&Bs[(wn * 64 + j * 16 + fr) * SA2 + kb];
#pragma unroll
                for (int i = 0; i < 4; ++i)
#pragma unroll
                    for (int j = 0; j < 4; ++j)
                        acc[i][j] = __builtin_amdgcn_mfma_f32_16x16x32_bf16(a[i], b[j], acc[i][j], 0, 0, 0);
            }
        }
#undef G1_LOAD
#undef G1_CVT

        // epilogue: wn=1 waves (up) -> LDS; wn=0 waves (gate) combine + store act
        unsigned short* upls = As;                 // reuse (16 KB <= 34 KB)
        __syncthreads();
        if (wn == 1) {
#pragma unroll
            for (int mi = 0; mi < 4; ++mi)
#pragma unroll
                for (int reg = 0; reg < 4; ++reg) {
                    int mrow = wm * 64 + mi * 16 + kg * 4 + reg;
#pragma unroll
                    for (int ni = 0; ni < 4; ++ni)
                        upls[mrow * 64 + ni * 16 + fr] = f2b(acc[mi][ni][reg]);
                }
        }
        __syncthreads();
        if (wn == 0) {
#pragma unroll
            for (int mi = 0; mi < 4; ++mi)
#pragma unroll
                for (int reg = 0; reg < 4; ++reg) {
                    int mrow = wm * 64 + mi * 16 + kg * 4 + reg;
                    int entry = ts[mrow];
                    if (entry < 0) continue;
                    float w = tw[mrow];
                    unsigned short* dst = act + (size_t)entry * II + i0;
#pragma unroll
                    for (int ni = 0; ni < 4; ++ni) {
                        float g = acc[mi][ni][reg];
                        float u = b2f(upls[mrow * 64 + ni * 16 + fr]);
                        dst[ni * 16 + fr] = f2b((g / (1.f + __expf(-g))) * u * w);
                    }
                }
        }
    }
}

// ---------------- gemm2: po[entry] = act[entry] @ w2[e]^T  (BK=128) ----------------
// grid (16, E); m-chunks looped in-kernel
__global__ __launch_bounds__(256, 2) void k_gemm2(
    const unsigned short* __restrict__ act, const float* __restrict__ w2,
    const int* __restrict__ cnt, const int* __restrict__ tok_list,
    float* __restrict__ po) {
    int e, nblk;
    swz_en(blockIdx.y * 16 + blockIdx.x, e, nblk);
    const int M = cnt[e];
    const int n0 = nblk * 128;

    __shared__ __align__(16) unsigned short As[TS2];
    __shared__ __align__(16) unsigned short Bs[TS2];
    __shared__ int ts[128];

    const int tid = threadIdx.x;
    const float* w2e = w2 + (size_t)e * HH * II;
    const int wid = tid >> 6;
    const int lane = tid & 63;
    const int wm = wid >> 1, wn = wid & 1;
    const int fr = lane & 15;
    const int kg = lane >> 4;
    const int srow = tid >> 4;
    const int sc8 = (tid & 15) * 8;

    ushort8 pa8[8];
    float4 pb[16];
    const ushort8 u8z = {0, 0, 0, 0, 0, 0, 0, 0};

    for (int m0 = 0; m0 < M; m0 += 128) {
        __syncthreads();
        if (tid < 128) {
            int mr = m0 + tid;
            ts[tid] = (mr < M) ? tok_list[e * TT + mr] : -1;
        }
        __syncthreads();

        f32x4 acc[4][4];
#pragma unroll
        for (int i = 0; i < 4; ++i)
#pragma unroll
            for (int j = 0; j < 4; ++j) acc[i][j] = (f32x4){0.f, 0.f, 0.f, 0.f};

#define G2_LOAD(kk)                                                              \
    do {                                                                         \
        const int kkv_ = (kk);                                                   \
        _Pragma("unroll")                                                        \
        for (int q = 0; q < 8; ++q) {                                            \
            int row = q * 16 + srow;                                             \
            int entry = ts[row];                                                 \
            pa8[q] = (entry >= 0)                                                \
                ? *(const ushort8*)(act + (size_t)entry * II + kkv_ + sc8)       \
                : u8z;                                                           \
            const float* gpb_ = w2e + (size_t)(n0 + row) * II + kkv_ + sc8;      \
            pb[2 * q] = ((const float4*)gpb_)[0];                                \
            pb[2 * q + 1] = ((const float4*)gpb_)[1];                            \
        }                                                                        \
    } while (0)

#define G2_CVT()                                                                 \
    do {                                                                         \
        _Pragma("unroll")                                                        \
        for (int q = 0; q < 8; ++q) {                                            \
            int row = q * 16 + srow;                                             \
            *(ushort8*)&As[row * SA2 + sc8] = pa8[q];                            \
            *(ushort8*)&Bs[row * SA2 + sc8] = pack8(pb[2 * q], pb[2 * q + 1]);   \
        }                                                                        \
    } while (0)

        const int NS = II / BK2;   // 8
        G2_LOAD(0);
        for (int s = 0; s < NS; ++s) {
            __syncthreads();
            G2_CVT();
            __syncthreads();
            if (s + 1 < NS) G2_LOAD((s + 1) * BK2);
#pragma unroll
            for (int kh = 0; kh < 4; ++kh) {
                const int kb = kh * 32 + kg * 8;
                bf16x8 a[4], b[4];
#pragma unroll
                for (int i = 0; i < 4; ++i)
                    a[i] = *(const bf16x8*)&As[(wm * 64 + i * 16 + fr) * SA2 + kb];
#pragma unroll
                for (int j = 0; j < 4; ++j)
                    b[j] = *(const bf16x8*)&Bs[(wn * 64 + j * 16 + fr) * SA2 + kb];
#pragma unroll
                for (int i = 0; i < 4; ++i)
#pragma unroll
                    for (int j = 0; j < 4; ++j)
                        acc[i][j] = __builtin_amdgcn_mfma_f32_16x16x32_bf16(a[i], b[j], acc[i][j], 0, 0, 0);
            }
        }
#undef G2_LOAD
#undef G2_CVT

#pragma unroll
        for (int mi = 0; mi < 4; ++mi) {
#pragma unroll
            for (int reg = 0; reg < 4; ++reg) {
                int m = wm * 64 + mi * 16 + kg * 4 + reg;
                int entry = ts[m];
                if (entry < 0) continue;
                float* op = po + (size_t)entry * HH + n0 + wn * 64;
#pragma unroll
                for (int ni = 0; ni < 4; ++ni)
                    op[ni * 16 + fr] = acc[mi][ni][reg];
            }
        }
        __syncthreads();   // guard ts rewrite (next m-chunk) vs this chunk's loads
    }
}

// ---------------- combine: out[t] = po[2t] + po[2t+1] ----------------
__global__ __launch_bounds__(256) void k_combine(const float* __restrict__ po,
                                                 float* __restrict__ out) {
    int i = blockIdx.x * 256 + threadIdx.x;
    int t = i / (HH / 4);
    int c = i % (HH / 4);
    float4 a = ((const float4*)(po + (size_t)(2 * t) * HH))[c];
    float4 b = ((const float4*)(po + (size_t)(2 * t + 1) * HH))[c];
    float4 r = make_float4(a.x + b.x, a.y + b.y, a.z + b.z, a.w + b.w);
    ((float4*)(out + (size_t)t * HH))[c] = r;
}

extern "C" void kernel_launch(void* const* d_in, const int* in_sizes, int n_in,
                              void* d_out, int out_size, void* d_ws, size_t ws_size,
                              hipStream_t stream) {
    const float* x    = (const float*)d_in[0];
    const float* wqkv = (const float*)d_in[1];
    const float* w1   = (const float*)d_in[2];
    const float* w2   = (const float*)d_in[3];
    float* out = (float*)d_out;

    char* ws = (char*)d_ws;
    float* mixp           = (float*)(ws);                      // 12582912 B
    float* wgt_list       = (float*)(ws + 12582912);           // 131072 B
    int*   tok_list       = (int*)  (ws + 12713984);           // 131072 B
    int*   cnt            = (int*)  (ws + 12845056);           // 128 B
    unsigned short* xb    = (unsigned short*)(ws + 12845184);  // 4194304 B
    unsigned short* act   = (unsigned short*)(ws + 17039488);  // 4194304 B
    float* po             = (float*)(ws + 21233792);           // 16777216 B

    (void)hipMemsetAsync(cnt, 0, 128, stream);

    k_cvtx<<<TT * HH / 8 / 256, 256, 0, stream>>>(x, xb);
    k_mix<<<dim3(TT / MB, KSP), 256, 0, stream>>>(x, wqkv, mixp);
    k_router_attn<<<TT, 128, 0, stream>>>(mixp, cnt, tok_list, wgt_list);
    k_gemm1<<<dim3(16, EE), 256, 0, stream>>>(xb, w1, cnt, tok_list, wgt_list, act);
    k_gemm2<<<dim3(16, EE), 256, 0, stream>>>(act, w2, cnt, tok_list, po);
    k_combine<<<TT * HH / 4 / 256, 256, 0, stream>>>(po, out);
}

// Round 11
// 218.531 us; speedup vs baseline: 1.1386x; 1.1386x over previous
//
#include <hip/hip_runtime.h>
#include <hip/hip_bf16.h>
#include <math.h>

#define TT 1024
#define HH 2048
#define EE 32
#define II 1024
#define BK2 128   // K-step (512 B per weight row per step)
#define SA2 136   // LDS row stride in bf16 elems (128 + 8 pad -> 2-way bank alias only)
#define TS2 (128 * SA2)
#define KSP 32    // router split-K chunks (K-chunk = 64)
#define MB 64     // router tokens per block

typedef __attribute__((ext_vector_type(8))) short bf16x8;
typedef __attribute__((ext_vector_type(8))) unsigned short ushort8;
typedef __attribute__((ext_vector_type(4))) float f32x4;

__device__ __forceinline__ unsigned short f2b(float f) {
    union { float f; unsigned u; } c; c.f = f;
    unsigned r = c.u + 0x7FFFu + ((c.u >> 16) & 1u);   // RNE to bf16
    return (unsigned short)(r >> 16);
}
__device__ __forceinline__ float b2f(unsigned short u) {
    union { unsigned u; float f; } c; c.u = ((unsigned)u) << 16;
    return c.f;
}
__device__ __forceinline__ unsigned cvtpk(float lo, float hi) {
    unsigned r;
    asm("v_cvt_pk_bf16_f32 %0, %1, %2" : "=v"(r) : "v"(lo), "v"(hi));
    return r;
}
__device__ __forceinline__ ushort8 pack8(float4 a, float4 b) {
    union { unsigned u[4]; ushort8 s; } cv;
    cv.u[0] = cvtpk(a.x, a.y); cv.u[1] = cvtpk(a.z, a.w);
    cv.u[2] = cvtpk(b.x, b.y); cv.u[3] = cvtpk(b.z, b.w);
    return cv.s;
}

// ---------------- router mix (split-K tiled fp32 GEMM) + fused x->bf16 ----------------
__global__ __launch_bounds__(256) void k_mix(const float* __restrict__ x,
                                             const float* __restrict__ wqkv,
                                             float* __restrict__ mixp,
                                             unsigned short* __restrict__ xb) {
    __shared__ float xs[MB][68];
    __shared__ float ws_[96][68];
    const int tm0 = blockIdx.x * MB;
    const int k0 = blockIdx.y * 64;
    const int tid = threadIdx.x;
#pragma unroll
    for (int q = 0; q < 4; ++q) {
        int p = tid + q * 256;
        int row = p >> 4, c4 = (p & 15) * 4;
        *(float4*)&xs[row][c4] = *(const float4*)(x + (size_t)(tm0 + row) * HH + k0 + c4);
    }
#pragma unroll
    for (int q = 0; q < 6; ++q) {
        int p = tid + q * 256;
        int row = p >> 4, c4 = (p & 15) * 4;
        *(float4*)&ws_[row][c4] = *(const float4*)(wqkv + (size_t)row * HH + k0 + c4);
    }
    __syncthreads();
    // fused: write this x-tile as bf16 (each (t,k) tile covered exactly once)
#pragma unroll
    for (int q = 0; q < 2; ++q) {
        int p = tid + q * 256;
        int row = p >> 3, c8 = (p & 7) * 8;
        float4 lo = *(const float4*)&xs[row][c8];
        float4 hi = *(const float4*)&xs[row][c8 + 4];
        *(ushort8*)(xb + (size_t)(tm0 + row) * HH + k0 + c8) = pack8(lo, hi);
    }
    const int tg = tid >> 4, cg = tid & 15;
    float acc[4][6];
#pragma unroll
    for (int i = 0; i < 4; ++i)
#pragma unroll
        for (int c = 0; c < 6; ++c) acc[i][c] = 0.f;
    for (int k = 0; k < 64; k += 4) {
        float4 xv[4], wv[6];
#pragma unroll
        for (int i = 0; i < 4; ++i) xv[i] = *(const float4*)&xs[tg * 4 + i][k];
#pragma unroll
        for (int c = 0; c < 6; ++c) wv[c] = *(const float4*)&ws_[cg * 6 + c][k];
#pragma unroll
        for (int i = 0; i < 4; ++i)
#pragma unroll
            for (int c = 0; c < 6; ++c)
                acc[i][c] += xv[i].x * wv[c].x + xv[i].y * wv[c].y +
                             xv[i].z * wv[c].z + xv[i].w * wv[c].w;
    }
    float* dst = mixp + ((size_t)blockIdx.y * TT + tm0) * 96;
#pragma unroll
    for (int i = 0; i < 4; ++i)
#pragma unroll
        for (int c = 0; c < 6; ++c)
            dst[(tg * 4 + i) * 96 + cg * 6 + c] = acc[i][c];
}

// ---------------- router: reduce partials + attention + top-2 + scatter ----------------
__global__ void k_router_attn(const float* __restrict__ mixp,
                              int* __restrict__ cnt,
                              int* __restrict__ tok_list,
                              float* __restrict__ wgt_list) {
    const int t = blockIdx.x;
    __shared__ float mrow[96];
    __shared__ float lg[EE];
    const int tid = threadIdx.x;
    if (tid < 96) {
        float s = 0.f;
        for (int sp = 0; sp < KSP; ++sp)          // fixed order -> deterministic
            s += mixp[((size_t)sp * TT + t) * 96 + tid];
        mrow[tid] = s;
    }
    __syncthreads();
    if (tid < EE) {
        float q = mrow[tid];
        float m = -1e30f;
        for (int f = 0; f < EE; ++f) m = fmaxf(m, q * mrow[32 + f]);
        float s = 0.f, a = 0.f;
        for (int f = 0; f < EE; ++f) {
            float ex = expf(q * mrow[32 + f] - m);
            s += ex;
            a += ex * mrow[64 + f];
        }
        lg[tid] = a / s;
    }
    __syncthreads();
    if (tid == 0) {
        int b0 = 0; float v0 = lg[0];
        for (int e2 = 1; e2 < EE; ++e2)
            if (lg[e2] > v0) { v0 = lg[e2]; b0 = e2; }
        int b1 = -1; float v1 = -1e30f;
        for (int e2 = 0; e2 < EE; ++e2)
            if (e2 != b0 && lg[e2] > v1) { v1 = lg[e2]; b1 = e2; }
        float ex = expf(v1 - v0);
        float w0 = 1.f / (1.f + ex);
        float w1 = ex / (1.f + ex);
        int p0 = atomicAdd(&cnt[b0], 1);
        tok_list[b0 * TT + p0] = t * 2 + 0;
        wgt_list[b0 * TT + p0] = w0;
        int p1 = atomicAdd(&cnt[b1], 1);
        tok_list[b1 * TT + p1] = t * 2 + 1;
        wgt_list[b1 * TT + p1] = w1;
    }
}

// ---------------- gemm1: act[entry, i0:i0+64] = silu(gate)*up*w  (fused gate/up, BK=128) ----------------
// grid (II/64=16, E, 8): block covers 64 gate rows + 64 up rows of w1[e]
__global__ __launch_bounds__(256, 2) void k_gemm1(
    const unsigned short* __restrict__ xb, const float* __restrict__ w1,
    const int* __restrict__ cnt, const int* __restrict__ tok_list,
    const float* __restrict__ wgt_list, unsigned short* __restrict__ act) {
    const int e = blockIdx.y;
    const int M = cnt[e];
    const int m0 = blockIdx.z * 128;
    if (m0 >= M) return;
    const int i0 = blockIdx.x * 64;

    __shared__ __align__(16) unsigned short As[TS2];
    __shared__ __align__(16) unsigned short Bs[TS2];
    __shared__ int ts[128];
    __shared__ float tw[128];

    const int tid = threadIdx.x;
    if (tid < 128) {
        int mr = m0 + tid;
        if (mr < M) {
            ts[tid] = tok_list[e * TT + mr];
            tw[tid] = wgt_list[e * TT + mr];
        } else { ts[tid] = -1; tw[tid] = 0.f; }
    }
    __syncthreads();

    const float* w1e = w1 + (size_t)e * (2 * II) * HH;
    const int wid = tid >> 6;
    const int lane = tid & 63;
    const int wm = wid >> 1, wn = wid & 1;
    const int fr = lane & 15;
    const int kg = lane >> 4;
    const int srow = tid >> 4;          // 16 threads per row
    const int sc8 = (tid & 15) * 8;     // col offset (8 elems): 512 B/row contiguous

    f32x4 acc[4][4];
#pragma unroll
    for (int i = 0; i < 4; ++i)
#pragma unroll
        for (int j = 0; j < 4; ++j) acc[i][j] = (f32x4){0.f, 0.f, 0.f, 0.f};

    ushort8 pa8[8];
    float4 pb[16];
    const ushort8 u8z = {0, 0, 0, 0, 0, 0, 0, 0};

#define G1_LOAD(kk)                                                              \
    do {                                                                         \
        const int kkv_ = (kk);                                                   \
        _Pragma("unroll")                                                        \
        for (int q = 0; q < 8; ++q) {                                            \
            int row = q * 16 + srow;                                             \
            int entry = ts[row];                                                 \
            pa8[q] = (entry >= 0)                                                \
                ? *(const ushort8*)(xb + (size_t)(entry >> 1) * HH + kkv_ + sc8) \
                : u8z;                                                           \
            int brow = (row < 64) ? (i0 + row) : (II + i0 + row - 64);           \
            const float* gpb_ = w1e + (size_t)brow * HH + kkv_ + sc8;            \
            pb[2 * q] = ((const float4*)gpb_)[0];                                \
            pb[2 * q + 1] = ((const float4*)gpb_)[1];                            \
        }                                                                        \
    } while (0)

#define G1_CVT()                                                                 \
    do {                                                                         \
        _Pragma("unroll")                                                        \
        for (int q = 0; q < 8; ++q) {                                            \
            int row = q * 16 + srow;                                             \
            *(ushort8*)&As[row * SA2 + sc8] = pa8[q];                            \
            *(ushort8*)&Bs[row * SA2 + sc8] = pack8(pb[2 * q], pb[2 * q + 1]);   \
        }                                                                        \
    } while (0)

    const int NS = HH / BK2;   // 16
    G1_LOAD(0);
    for (int s = 0; s < NS; ++s) {
        __syncthreads();
        G1_CVT();
        __syncthreads();
        if (s + 1 < NS) G1_LOAD((s + 1) * BK2);
#pragma unroll
        for (int kh = 0; kh < 4; ++kh) {
            const int kb = kh * 32 + kg * 8;
            bf16x8 a[4], b[4];
#pragma unroll
            for (int i = 0; i < 4; ++i)
                a[i] = *(const bf16x8*)&As[(wm * 64 + i * 16 + fr) * SA2 + kb];
#pragma unroll
            for (int j = 0; j < 4; ++j)
                b[j] = *(const bf16x8*)&Bs[(wn * 64 + j * 16 + fr) * SA2 + kb];
#pragma unroll
            for (int i = 0; i < 4; ++i)
#pragma unroll
                for (int j = 0; j < 4; ++j)
                    acc[i][j] = __builtin_amdgcn_mfma_f32_16x16x32_bf16(a[i], b[j], acc[i][j], 0, 0, 0);
        }
    }
#undef G1_LOAD
#undef G1_CVT

    // epilogue: wn=1 waves (up) -> LDS; wn=0 waves (gate) combine + store act
    unsigned short* upls = As;                     // reuse (16 KB <= 34 KB)
    __syncthreads();
    if (wn == 1) {
#pragma unroll
        for (int mi = 0; mi < 4; ++mi)
#pragma unroll
            for (int reg = 0; reg < 4; ++reg) {
                int mrow = wm * 64 + mi * 16 + kg * 4 + reg;
#pragma unroll
                for (int ni = 0; ni < 4; ++ni)
                    upls[mrow * 64 + ni * 16 + fr] = f2b(acc[mi][ni][reg]);
            }
    }
    __syncthreads();
    if (wn == 0) {
#pragma unroll
        for (int mi = 0; mi < 4; ++mi)
#pragma unroll
            for (int reg = 0; reg < 4; ++reg) {
                int mrow = wm * 64 + mi * 16 + kg * 4 + reg;
                int entry = ts[mrow];
                if (entry < 0) continue;
                float w = tw[mrow];
                unsigned short* dst = act + (size_t)entry * II + i0;
#pragma unroll
                for (int ni = 0; ni < 4; ++ni) {
                    float g = acc[mi][ni][reg];
                    float u = b2f(upls[mrow * 64 + ni * 16 + fr]);
                    dst[ni * 16 + fr] = f2b((g / (1.f + __expf(-g))) * u * w);
                }
            }
    }
}

// ---------------- gemm2: out[t] += act[entry] @ w2[e]^T  (BK=128, atomic combine) ----------------
__global__ __launch_bounds__(256, 2) void k_gemm2(
    const unsigned short* __restrict__ act, const float* __restrict__ w2,
    const int* __restrict__ cnt, const int* __restrict__ tok_list,
    float* __restrict__ out) {
    const int e = blockIdx.y;
    const int M = cnt[e];
    const int m0 = blockIdx.z * 128;
    if (m0 >= M) return;
    const int n0 = blockIdx.x * 128;

    __shared__ __align__(16) unsigned short As[TS2];
    __shared__ __align__(16) unsigned short Bs[TS2];
    __shared__ int ts[128];

    const int tid = threadIdx.x;
    if (tid < 128) {
        int mr = m0 + tid;
        ts[tid] = (mr < M) ? tok_list[e * TT + mr] : -1;
    }
    __syncthreads();

    const float* w2e = w2 + (size_t)e * HH * II;
    const int wid = tid >> 6;
    const int lane = tid & 63;
    const int wm = wid >> 1, wn = wid & 1;
    const int fr = lane & 15;
    const int kg = lane >> 4;
    const int srow = tid >> 4;
    const int sc8 = (tid & 15) * 8;

    f32x4 acc[4][4];
#pragma unroll
    for (int i = 0; i < 4; ++i)
#pragma unroll
        for (int j = 0; j < 4; ++j) acc[i][j] = (f32x4){0.f, 0.f, 0.f, 0.f};

    ushort8 pa8[8];
    float4 pb[16];
    const ushort8 u8z = {0, 0, 0, 0, 0, 0, 0, 0};

#define G2_LOAD(kk)                                                              \
    do {                                                                         \
        const int kkv_ = (kk);                                                   \
        _Pragma("unroll")                                                        \
        for (int q = 0; q < 8; ++q) {                                            \
            int row = q * 16 + srow;                                             \
            int entry = ts[row];                                                 \
            pa8[q] = (entry >= 0)                                                \
                ? *(const ushort8*)(act + (size_t)entry * II + kkv_ + sc8)       \
                : u8z;                                                           \
            const float* gpb_ = w2e + (size_t)(n0 + row) * II + kkv_ + sc8;      \
            pb[2 * q] = ((const float4*)gpb_)[0];                                \
            pb[2 * q + 1] = ((const float4*)gpb_)[1];                            \
        }                                                                        \
    } while (0)

#define G2_CVT()                                                                 \
    do {                                                                         \
        _Pragma("unroll")                                                        \
        for (int q = 0; q < 8; ++q) {                                            \
            int row = q * 16 + srow;                                             \
            *(ushort8*)&As[row * SA2 + sc8] = pa8[q];                            \
            *(ushort8*)&Bs[row * SA2 + sc8] = pack8(pb[2 * q], pb[2 * q + 1]);   \
        }                                                                        \
    } while (0)

    const int NS = II / BK2;   // 8
    G2_LOAD(0);
    for (int s = 0; s < NS; ++s) {
        __syncthreads();
        G2_CVT();
        __syncthreads();
        if (s + 1 < NS) G2_LOAD((s + 1) * BK2);
#pragma unroll
        for (int kh = 0; kh < 4; ++kh) {
            const int kb = kh * 32 + kg * 8;
            bf16x8 a[4], b[4];
#pragma unroll
            for (int i = 0; i < 4; ++i)
                a[i] = *(const bf16x8*)&As[(wm * 64 + i * 16 + fr) * SA2 + kb];
#pragma unroll
            for (int j = 0; j < 4; ++j)
                b[j] = *(const bf16x8*)&Bs[(wn * 64 + j * 16 + fr) * SA2 + kb];
#pragma unroll
            for (int i = 0; i < 4; ++i)
#pragma unroll
                for (int j = 0; j < 4; ++j)
                    acc[i][j] = __builtin_amdgcn_mfma_f32_16x16x32_bf16(a[i], b[j], acc[i][j], 0, 0, 0);
        }
    }
#undef G2_LOAD
#undef G2_CVT

    // epilogue: atomic combine into out (each element gets exactly 2 adds; 2-term
    // fp32 add is commutative -> bitwise deterministic)
#pragma unroll
    for (int mi = 0; mi < 4; ++mi) {
#pragma unroll
        for (int reg = 0; reg < 4; ++reg) {
            int m = wm * 64 + mi * 16 + kg * 4 + reg;
            int entry = ts[m];
            if (entry < 0) continue;
            int t = entry >> 1;
            float* op = out + (size_t)t * HH + n0 + wn * 64;
#pragma unroll
            for (int ni = 0; ni < 4; ++ni)
                atomicAdd(&op[ni * 16 + fr], acc[mi][ni][reg]);
        }
    }
}

extern "C" void kernel_launch(void* const* d_in, const int* in_sizes, int n_in,
                              void* d_out, int out_size, void* d_ws, size_t ws_size,
                              hipStream_t stream) {
    const float* x    = (const float*)d_in[0];
    const float* wqkv = (const float*)d_in[1];
    const float* w1   = (const float*)d_in[2];
    const float* w2   = (const float*)d_in[3];
    float* out = (float*)d_out;

    char* ws = (char*)d_ws;
    float* mixp           = (float*)(ws);                      // 12582912 B
    float* wgt_list       = (float*)(ws + 12582912);           // 131072 B
    int*   tok_list       = (int*)  (ws + 12713984);           // 131072 B
    int*   cnt            = (int*)  (ws + 12845056);           // 128 B
    unsigned short* xb    = (unsigned short*)(ws + 12845184);  // 4194304 B
    unsigned short* act   = (unsigned short*)(ws + 17039488);  // 4194304 B

    (void)hipMemsetAsync(cnt, 0, 128, stream);
    (void)hipMemsetAsync(out, 0, (size_t)out_size * sizeof(float), stream);

    k_mix<<<dim3(TT / MB, KSP), 256, 0, stream>>>(x, wqkv, mixp, xb);
    k_router_attn<<<TT, 128, 0, stream>>>(mixp, cnt, tok_list, wgt_list);
    k_gemm1<<<dim3(II / 64, EE, 8), 256, 0, stream>>>(xb, w1, cnt, tok_list, wgt_list, act);
    k_gemm2<<<dim3(HH / 128, EE, 8), 256, 0, stream>>>(act, w2, cnt, tok_list, out);
}